// Round 6
// baseline (179.746 us; speedup 1.0000x reference)
//
#include <hip/hip_runtime.h>
#include <hip/hip_bf16.h>

#define SENTINEL 24635

typedef unsigned char f8_t;  // OCP e4m3 storage
using bf16x8  = __attribute__((ext_vector_type(8))) __bf16;
using bf16x2  = __attribute__((ext_vector_type(2))) __bf16;
using floatx4 = __attribute__((ext_vector_type(4))) float;

__device__ inline int pack4_fp8(float4 a, float s) {
  int w = __builtin_amdgcn_cvt_pk_fp8_f32(a.x * s, a.y * s, 0, false);
  return __builtin_amdgcn_cvt_pk_fp8_f32(a.z * s, a.w * s, w, true);
}

// pack 8 scaled floats -> 8 e4m3 bytes
__device__ inline void store_fp8x8(f8_t* d, float4 a, float4 b, float s) {
  int2 v; v.x = pack4_fp8(a, s); v.y = pack4_fp8(b, s);
  *(int2*)d = v;
}

// async global->LDS, 16 B per lane. LDS dest = wave-uniform base + lane*16.
__device__ inline void gll16(const void* g, void* l) {
  __builtin_amdgcn_global_load_lds(
      (const __attribute__((address_space(1))) unsigned int*)g,
      (__attribute__((address_space(3))) unsigned int*)l, 16, 0, 0);
}

// ---------------------------------------------------------------------------
// Entity pool (device helper): user_n[b] = bf16 masked mean of
// ent_embs[ent_list[b,:cnt]]. One wave per b-row.
// ---------------------------------------------------------------------------
__device__ inline void pool_body(const float* __restrict__ ent,
                                 const int* __restrict__ ent_list,
                                 __bf16* __restrict__ user_n, int b) {
  const int lane = threadIdx.x & 63;
  int myidx = (lane < 50) ? ent_list[b * 50 + lane] : 0;
  unsigned long long m = __ballot(lane < 50 && myidx == SENTINEL);
  const int cnt = (m == 0) ? 50 : (int)__builtin_ctzll(m);

  float sx = 0.f, sy = 0.f;
  for (int l0 = 0; l0 < 50; l0 += 10) {
    if (l0 >= cnt) break;  // wave-uniform
    float2 e[10];
#pragma unroll
    for (int j = 0; j < 10; ++j) {
      int idx = __shfl(myidx, l0 + j);
      e[j] = *(const float2*)(ent + (size_t)idx * 128 + lane * 2);
    }
#pragma unroll
    for (int j = 0; j < 10; ++j) {
      if (l0 + j < cnt) { sx += e[j].x; sy += e[j].y; }
    }
  }
  float vx, vy;
  if (cnt == 0) {
    float2 e = *(const float2*)(ent + (size_t)SENTINEL * 128 + lane * 2);
    vx = e.x; vy = e.y;
  } else {
    float inv = 1.f / (float)cnt;
    vx = sx * inv; vy = sy * inv;
  }
  bf16x2 o; o[0] = (__bf16)vx; o[1] = (__bf16)vy;
  *(bf16x2*)(user_n + (size_t)b * 128 + lane * 2) = o;
}

// ---------------------------------------------------------------------------
// Dispatch 1 — prep: f32->fp8 convert of ctx (x1) and W1 (x16) only.
// ---------------------------------------------------------------------------
__global__ __launch_bounds__(256) void prep_kernel(
    const float* __restrict__ s0, f8_t* __restrict__ d0,
    const float* __restrict__ s1, f8_t* __restrict__ d1) {
  // sizes in 8-elem units: ctx 524288, W1 98304
  int g = blockIdx.x * 256 + threadIdx.x;
  const float* s; f8_t* d; int i; float sc;
  if (g < 524288)      { s = s0; d = d0; i = g;          sc = 1.f;  }
  else                 { s = s1; d = d1; i = g - 524288; sc = 16.f; }
  i *= 8;
  float4 a = *(const float4*)(s + i);
  float4 b = *(const float4*)(s + i + 4);
  store_fp8x8(d + i, a, b, sc);
}

// ---------------------------------------------------------------------------
// fp8 GEMM body: C = act( (A . W^T) * (1/16) ), A,W fp8 e4m3 row-major
// (K contiguous). Tile (WR*MT*16) x (WC*NT*16), BK = NS*32 slabs,
// 256 threads = 4 waves WR x WC. LDS rows 32 B unpadded (m97-style);
// gll16 chunks = 32 rows x 32 B. MFMA 16x16x32 fp8.
// R2-R4 ledger: >=2 blocks/CU required (1/CU costs +6.5us); beyond that,
// barrier count / tile shape / occupancy moves are all within +-1.2us.
// ---------------------------------------------------------------------------
template <int WR, int WC, int MT, int NT, int RELU, bool OUT_BF16, int NS>
__device__ inline void gemm_body_f8(const f8_t* __restrict__ A,
                                    const f8_t* __restrict__ W,
                                    void* __restrict__ Cout,
                                    int M, int N, int K, int bn0, int bm0,
                                    char* lds) {
  constexpr int BM = WR * MT * 16;
  constexpr int BN = WC * NT * 16;
  auto As = (f8_t (*)[BM][32])lds;                        // As[s][r][k]
  auto Bs = (f8_t (*)[BN][32])(lds + (size_t)NS * BM * 32);
  const int tid  = threadIdx.x;
  const int w    = tid >> 6;
  const int lane = tid & 63;
  const int quad = lane >> 4;
  const int l16  = lane & 15;
  const int wr   = w / WC;
  const int wc   = w % WC;
  const int lrow = lane >> 1;        // 0..31 row within 1 KB chunk
  const int lcol = (lane & 1) * 16;  // fp8 col within 32-B slab row

  floatx4 acc[MT][NT];
#pragma unroll
  for (int mt = 0; mt < MT; ++mt)
#pragma unroll
    for (int nt = 0; nt < NT; ++nt) acc[mt][nt] = (floatx4){0.f, 0.f, 0.f, 0.f};

  constexpr int nAc = NS * (BM / 32);  // 1 KB chunks, slab-major
  constexpr int nBc = NS * (BN / 32);
  for (int k0 = 0; k0 < K; k0 += NS * 32) {
    __syncthreads();
#pragma unroll
    for (int c = w; c < nAc; c += 4) {
      int s = c / (BM / 32);
      int r = (c % (BM / 32)) * 32;
      gll16(A + (size_t)(bm0 + r + lrow) * K + k0 + s * 32 + lcol, &As[s][r][0]);
    }
#pragma unroll
    for (int c = w; c < nBc; c += 4) {
      int s = c / (BN / 32);
      int r = (c % (BN / 32)) * 32;
      gll16(W + (size_t)(bn0 + r + lrow) * K + k0 + s * 32 + lcol, &Bs[s][r][0]);
    }
    __syncthreads();
#pragma unroll
    for (int s = 0; s < NS; ++s) {
      long af[MT], bfr[NT];
#pragma unroll
      for (int mt = 0; mt < MT; ++mt)
        af[mt] = *(const long*)&As[s][wr * (MT * 16) + mt * 16 + l16][quad * 8];
#pragma unroll
      for (int nt = 0; nt < NT; ++nt)
        bfr[nt] = *(const long*)&Bs[s][wc * (NT * 16) + nt * 16 + l16][quad * 8];
#pragma unroll
      for (int mt = 0; mt < MT; ++mt)
#pragma unroll
        for (int nt = 0; nt < NT; ++nt)
          acc[mt][nt] = __builtin_amdgcn_mfma_f32_16x16x32_fp8_fp8(
              af[mt], bfr[nt], acc[mt][nt], 0, 0, 0);
    }
  }

  const float osc = 0.0625f;  // undo W x16
#pragma unroll
  for (int mt = 0; mt < MT; ++mt) {
    const int row0 = bm0 + wr * (MT * 16) + mt * 16 + quad * 4;
#pragma unroll
    for (int nt = 0; nt < NT; ++nt) {
      const int col = bn0 + wc * (NT * 16) + nt * 16 + l16;
#pragma unroll
      for (int r = 0; r < 4; ++r) {
        float v = acc[mt][nt][r] * osc;
        if (RELU) v = fmaxf(v, 0.f);
        if (OUT_BF16) {
          ((__bf16*)Cout)[(size_t)(row0 + r) * N + col] = (__bf16)v;
        } else {
          int p = __builtin_amdgcn_cvt_pk_fp8_f32(v, v, 0, false);
          ((f8_t*)Cout)[(size_t)(row0 + r) * N + col] = (f8_t)(p & 0xff);
        }
      }
    }
  }
}

// ---------------------------------------------------------------------------
// Dispatch 2 — gemm1 (fp8, 64x96, BK=128, blocks 0..511) fused with the
// entity pool (blocks 512..1535) and the W2/W3 converts (blocks 1536..1759).
// Races: none — nothing here reads user_n / x1b / W2b / W3b.
// ---------------------------------------------------------------------------
__global__ __launch_bounds__(256) void gemm1_pool(const f8_t* __restrict__ A,
                                                  const f8_t* __restrict__ W,
                                                  f8_t* __restrict__ C,
                                                  const float* __restrict__ ent,
                                                  const int* __restrict__ ent_list,
                                                  __bf16* __restrict__ user_n,
                                                  const float* __restrict__ s2,
                                                  f8_t* __restrict__ d2,
                                                  const float* __restrict__ s3,
                                                  f8_t* __restrict__ d3) {
  __shared__ char lds[20480];  // gemm: 4*(64+96)*32 = 20480
  const int bx = blockIdx.x;
  if (bx < 512) {
    gemm_body_f8<2, 2, 2, 3, 1, false, 4>(A, W, C, 4096, 768, 1024,
                                          (bx % 8) * 96, (bx / 8) * 64, lds);
    return;
  }
  if (bx < 1536) {
    pool_body(ent, ent_list, user_n, (bx - 512) * 4 + (threadIdx.x >> 6));
    return;
  }
  // W2: 49152 8-elem units, W3: 8192
  int g = (bx - 1536) * 256 + threadIdx.x;
  const float* s; f8_t* d; int i;
  if (g < 49152) { s = s2; d = d2; i = g; }
  else           { s = s3; d = d3; i = g - 49152; }
  i *= 8;
  float4 a = *(const float4*)(s + i);
  float4 b = *(const float4*)(s + i + 4);
  store_fp8x8(d + i, a, b, 16.f);
}

// ---------------------------------------------------------------------------
// Dispatch 3 — gemm2 (fp8, 64x64, BK=128, blocks 0..511) fused with the
// user_n -> user_t bf16 transpose (blocks 512..639).
// ---------------------------------------------------------------------------
__global__ __launch_bounds__(256) void gemm2_tr(const f8_t* __restrict__ A,
                                                const f8_t* __restrict__ W,
                                                f8_t* __restrict__ C,
                                                const __bf16* __restrict__ un,
                                                __bf16* __restrict__ ut) {
  __shared__ char lds[16384];  // gemm: 4*(64+64)*32 = 16384; tr: 9216
  const int bx = blockIdx.x;
  if (bx < 512) {
    gemm_body_f8<2, 2, 2, 2, 1, false, 4>(A, W, C, 4096, 512, 768,
                                          (bx % 8) * 64, (bx / 8) * 64, lds);
    return;
  }
  const int idx = bx - 512;             // 0..127
  const int r0 = (idx & 63) * 64;       // key rows
  const int c0 = (idx >> 6) * 64;       // dim cols
  auto T = (__bf16 (*)[72])lds;
  const int tid = threadIdx.x;
#pragma unroll
  for (int p = 0; p < 2; ++p) {
    int r = (tid >> 3) + p * 32;
    int c = (tid & 7) * 8;
    *(bf16x8*)&T[r][c] = *(const bf16x8*)(un + (size_t)(r0 + r) * 128 + c0 + c);
  }
  __syncthreads();
#pragma unroll
  for (int p = 0; p < 2; ++p) {
    int c = (tid >> 3) + p * 32;
    int r = (tid & 7) * 8;
    bf16x8 v;
#pragma unroll
    for (int j = 0; j < 8; ++j) v[j] = T[r + j][c];
    *(bf16x8*)(ut + (size_t)(c0 + c) * 4096 + r0 + r) = v;
  }
}

// ---------------------------------------------------------------------------
// Dispatch 4 — flash attention with FUSED Q-compute (R6: gemm3 folded in).
// Each block recomputes its 128-row Q-tile from x2b/W3b (fp8 MFMA, 16x
// redundant across splits — trivial vs MFMA ceiling) into the Un/Ut LDS
// region (free during prologue; per-wave row ranges are wave-private so the
// LDS round-trip needs no barrier; one barrier before ST_CHUNK reclaims it).
// Initial KV-chunk loads issue BEFORE the Q-phase -> cold-start stall hidden.
// grid (32 q-tiles, 16 key-splits); LDS 54272 -> 2 blocks/CU.
// NO fences/atomics (R11: device-scope fences cost ~60 us here).
// T14 async-STAGE + s_setprio as before. Last chunk: barriers elided.
// ---------------------------------------------------------------------------
__global__ __launch_bounds__(256) void flash_attn(const f8_t* __restrict__ X2,
                                                  const f8_t* __restrict__ W3,
                                                  const __bf16* __restrict__ Un_g,
                                                  const __bf16* __restrict__ Ut_g,
                                                  __bf16* __restrict__ O_part,
                                                  float* __restrict__ lp) {
  __shared__ char smem[54272];
  auto Un = (__bf16 (*)[136])smem;            // [64 key][136]  (17408 B)
  auto Ut = (__bf16 (*)[72])(smem + 17408);   // [128 d][72]    (18432 B)
  auto Ps = (__bf16 (*)[32][72])(smem + 35840);  // [4][32][72] (18432 B)
  auto Qlds = (__bf16 (*)[136])smem;          // [128][136] aliases Un+Ut
  const int tid  = threadIdx.x;
  const int w    = tid >> 6;
  const int lane = tid & 63;
  const int quad = lane >> 4;
  const int l16  = lane & 15;
  const int qrow0 = blockIdx.x * 128;
  const int split = blockIdx.y;
  const float scale = 0.08838834764831845f;  // 1/sqrt(128)

  // T14 reg-staging lanes
  const int sr = tid >> 4, sc = (tid & 15) * 8;   // Un: rows sr+p*16, col sc
  const int td = tid >> 3, tk = (tid & 7) * 8;    // Ut: d td+p*32, key tk
  bf16x8 un_r[4], ut_r[4];

#define LD_CHUNK(key0)                                                         \
  do {                                                                         \
    _Pragma("unroll")                                                          \
    for (int p = 0; p < 4; ++p)                                                \
      un_r[p] = *(const bf16x8*)(Un_g + (size_t)((key0) + sr + p * 16) * 128 + sc); \
    _Pragma("unroll")                                                          \
    for (int p = 0; p < 4; ++p)                                                \
      ut_r[p] = *(const bf16x8*)(Ut_g + (size_t)(td + p * 32) * 4096 + (key0) + tk); \
  } while (0)

#define ST_CHUNK()                                                             \
  do {                                                                         \
    _Pragma("unroll")                                                          \
    for (int p = 0; p < 4; ++p) *(bf16x8*)&Un[sr + p * 16][sc] = un_r[p];      \
    _Pragma("unroll")                                                          \
    for (int p = 0; p < 4; ++p) *(bf16x8*)&Ut[td + p * 32][tk] = ut_r[p];      \
  } while (0)

  LD_CHUNK(split * 256);  // first KV chunk in flight under the Q-phase

  // ---- Q-phase: Q[32 rows x 128] = (x2 . W3^T) * (1/16) per wave ----
  {
    floatx4 qa[2][8];
#pragma unroll
    for (int mt = 0; mt < 2; ++mt)
#pragma unroll
      for (int nt = 0; nt < 8; ++nt) qa[mt][nt] = (floatx4){0.f, 0.f, 0.f, 0.f};
    const f8_t* xr0 = X2 + (size_t)(qrow0 + w * 32 + l16) * 512;
    const f8_t* xr1 = X2 + (size_t)(qrow0 + w * 32 + 16 + l16) * 512;
    const f8_t* wb  = W3 + (size_t)l16 * 512;
#pragma unroll
    for (int ks = 0; ks < 16; ++ks) {
      long a0 = *(const long*)(xr0 + ks * 32 + quad * 8);
      long a1 = *(const long*)(xr1 + ks * 32 + quad * 8);
#pragma unroll
      for (int nt = 0; nt < 8; ++nt) {
        long bf = *(const long*)(wb + (size_t)nt * 16 * 512 + ks * 32 + quad * 8);
        qa[0][nt] = __builtin_amdgcn_mfma_f32_16x16x32_fp8_fp8(a0, bf, qa[0][nt], 0, 0, 0);
        qa[1][nt] = __builtin_amdgcn_mfma_f32_16x16x32_fp8_fp8(a1, bf, qa[1][nt], 0, 0, 0);
      }
    }
    // C-layout write to wave-private Qlds rows, no barrier needed.
#pragma unroll
    for (int mt = 0; mt < 2; ++mt)
#pragma unroll
      for (int nt = 0; nt < 8; ++nt)
#pragma unroll
        for (int r = 0; r < 4; ++r)
          Qlds[w * 32 + mt * 16 + quad * 4 + r][nt * 16 + l16] =
              (__bf16)(qa[mt][nt][r] * 0.0625f);
  }

  bf16x8 aq[2][4];
#pragma unroll
  for (int mt = 0; mt < 2; ++mt)
#pragma unroll
    for (int c = 0; c < 4; ++c)
      aq[mt][c] = *(const bf16x8*)&Qlds[w * 32 + mt * 16 + l16][c * 32 + quad * 8];

  floatx4 o[2][8];
#pragma unroll
  for (int mt = 0; mt < 2; ++mt)
#pragma unroll
    for (int t = 0; t < 8; ++t) o[mt][t] = (floatx4){0.f, 0.f, 0.f, 0.f};
  float lsum[2][4] = {{0.f, 0.f, 0.f, 0.f}, {0.f, 0.f, 0.f, 0.f}};

  __syncthreads();  // all waves done with Qlds; Un/Ut region reclaimable
  ST_CHUNK();       // implicit vmcnt wait on the prefetched KV regs
  __syncthreads();

  for (int chunk = 0; chunk < 4; ++chunk) {
    if (chunk < 3) LD_CHUNK(split * 256 + (chunk + 1) * 64);  // async prefetch

    // S = Q Uc^T for both m-tiles (bk read once), exp fp32, P -> LDS bf16.
#pragma unroll
    for (int t = 0; t < 4; ++t) {
      bf16x8 bk[4];
#pragma unroll
      for (int c = 0; c < 4; ++c)
        bk[c] = *(const bf16x8*)&Un[t * 16 + l16][c * 32 + quad * 8];
      floatx4 s0 = (floatx4){0.f, 0.f, 0.f, 0.f};
      floatx4 s1 = (floatx4){0.f, 0.f, 0.f, 0.f};
      __builtin_amdgcn_s_setprio(1);
#pragma unroll
      for (int c = 0; c < 4; ++c) {
        s0 = __builtin_amdgcn_mfma_f32_16x16x32_bf16(aq[0][c], bk[c], s0, 0, 0, 0);
        s1 = __builtin_amdgcn_mfma_f32_16x16x32_bf16(aq[1][c], bk[c], s1, 0, 0, 0);
      }
      __builtin_amdgcn_s_setprio(0);
#pragma unroll
      for (int r = 0; r < 4; ++r) {
        float p0 = __expf(s0[r] * scale);
        float p1 = __expf(s1[r] * scale);
        lsum[0][r] += p0;
        lsum[1][r] += p1;
        Ps[w][quad * 4 + r][t * 16 + l16] = (__bf16)p0;
        Ps[w][16 + quad * 4 + r][t * 16 + l16] = (__bf16)p1;
      }
    }
    // Ps wave-private: compiler lgkmcnt ordering suffices, no barrier.

    // O += P @ Uc (bv read once, used by both m-tiles)
#pragma unroll
    for (int c2 = 0; c2 < 2; ++c2) {
      bf16x8 ap0 = *(const bf16x8*)&Ps[w][l16][c2 * 32 + quad * 8];
      bf16x8 ap1 = *(const bf16x8*)&Ps[w][16 + l16][c2 * 32 + quad * 8];
      __builtin_amdgcn_s_setprio(1);
#pragma unroll
      for (int dt = 0; dt < 8; ++dt) {
        bf16x8 bv = *(const bf16x8*)&Ut[dt * 16 + l16][c2 * 32 + quad * 8];
        o[0][dt] = __builtin_amdgcn_mfma_f32_16x16x32_bf16(ap0, bv, o[0][dt], 0, 0, 0);
        o[1][dt] = __builtin_amdgcn_mfma_f32_16x16x32_bf16(ap1, bv, o[1][dt], 0, 0, 0);
      }
      __builtin_amdgcn_s_setprio(0);
    }

    if (chunk < 3) {
      __syncthreads();  // all waves done reading Un/Ut
      ST_CHUNK();       // implicit vmcnt wait on the prefetched regs
      __syncthreads();
    }
  }
#undef LD_CHUNK
#undef ST_CHUNK

  // Row sums: reduce over the 16 key-columns held across l16.
#pragma unroll
  for (int mt = 0; mt < 2; ++mt)
#pragma unroll
    for (int r = 0; r < 4; ++r) {
      float v = lsum[mt][r];
      v += __shfl_xor(v, 1);
      v += __shfl_xor(v, 2);
      v += __shfl_xor(v, 4);
      v += __shfl_xor(v, 8);
      lsum[mt][r] = v;
    }

  __bf16* Ob = O_part + (size_t)split * 524288;
#pragma unroll
  for (int mt = 0; mt < 2; ++mt) {
    const int row0 = qrow0 + w * 32 + mt * 16 + quad * 4;
#pragma unroll
    for (int dt = 0; dt < 8; ++dt) {
#pragma unroll
      for (int r = 0; r < 4; ++r) {
        Ob[(size_t)(row0 + r) * 128 + dt * 16 + l16] = (__bf16)o[mt][dt][r];
      }
    }
    if (l16 == 0) {
#pragma unroll
      for (int r = 0; r < 4; ++r) lp[(size_t)split * 4096 + row0 + r] = lsum[mt][r];
    }
  }
}

// ---------------------------------------------------------------------------
// Combine 16 key-splits: out = (sum_s O_s) / (sum_s lp[s][row]). 8 elems/thr.
// ---------------------------------------------------------------------------
__global__ __launch_bounds__(256) void combine_kernel(const __bf16* __restrict__ Op,
                                                      const float* __restrict__ lp,
                                                      float* __restrict__ out) {
  const int i = (blockIdx.x * 256 + threadIdx.x) * 8;  // 0 .. 524287 step 8
  const int row = i >> 7;
  float num[8] = {0.f, 0.f, 0.f, 0.f, 0.f, 0.f, 0.f, 0.f};
  float den = 0.f;
#pragma unroll
  for (int s = 0; s < 16; ++s) {
    bf16x8 v = *(const bf16x8*)(Op + (size_t)s * 524288 + i);
#pragma unroll
    for (int j = 0; j < 8; ++j) num[j] += (float)v[j];
    den += lp[(size_t)s * 4096 + row];
  }
  float inv = 1.f / den;
  float4 r0 = {num[0] * inv, num[1] * inv, num[2] * inv, num[3] * inv};
  float4 r1 = {num[4] * inv, num[5] * inv, num[6] * inv, num[7] * inv};
  *(float4*)(out + i) = r0;
  *(float4*)(out + i + 4) = r1;
}

extern "C" void kernel_launch(void* const* d_in, const int* in_sizes, int n_in,
                              void* d_out, int out_size, void* d_ws, size_t ws_size,
                              hipStream_t stream) {
  (void)in_sizes; (void)n_in; (void)out_size; (void)ws_size;
  const float* ctx      = (const float*)d_in[0];  // [4096,1024]
  const float* ent_embs = (const float*)d_in[1];  // [24636,128]
  const float* W1       = (const float*)d_in[2];  // [768,1024]
  const float* W2       = (const float*)d_in[3];  // [512,768]
  const float* W3       = (const float*)d_in[4];  // [128,512]
  const int*   ent_list = (const int*)d_in[5];    // [4096,50]
  float* out = (float*)d_out;

  // ws layout; peak use ~31 MB (ws is 256 MB).
  char* base = (char*)d_ws;
  __bf16* user_n = (__bf16*)(base);                       // 1 MB
  __bf16* user_t = (__bf16*)(base + (1ull << 20));        // 1 MB
  float*  lp     = (float*)(base + (3ull << 20));         // 256 KB [16][4096]
  f8_t*   ctxb   = (f8_t*)(base + (4ull << 20));          // 4 MB
  f8_t*   W1b    = (f8_t*)(base + (8ull << 20));          // 0.75 MB
  f8_t*   W2b    = (f8_t*)(base + 9175040ull);            // 8.75 MB, 384 KB
  f8_t*   W3b    = (f8_t*)(base + 9568256ull);            // 9.125 MB, 64 KB
  f8_t*   x1b    = (f8_t*)(base + (10ull << 20));         // 3 MB
  f8_t*   x2b    = (f8_t*)(base + (13ull << 20));         // 2 MB
  __bf16* O_part = (__bf16*)(base + (15ull << 20));       // 16 MB (bf16 x 16)

  // 5 dispatches. Critical path: prep -> gemm1 -> gemm2 -> flash(+Q) ->
  // combine; pool rides inside dispatch 2, tr inside dispatch 3.
  prep_kernel<<<2432, 256, 0, stream>>>(ctx, ctxb, W1, W1b);
  gemm1_pool<<<1760, 256, 0, stream>>>(ctxb, W1b, x1b, ent_embs, ent_list,
                                       user_n, W2, W2b, W3, W3b);
  gemm2_tr<<<640, 256, 0, stream>>>(x1b, W2b, x2b, user_n, user_t);
  flash_attn<<<dim3(32, 16), 256, 0, stream>>>(x2b, W3b, user_n, user_t,
                                               O_part, lp);
  combine_kernel<<<256, 256, 0, stream>>>(O_part, lp, out);
}

// Round 7
// 143.887 us; speedup vs baseline: 1.2492x; 1.2492x over previous
//
#include <hip/hip_runtime.h>
#include <hip/hip_bf16.h>

#define SENTINEL 24635

typedef unsigned char f8_t;  // OCP e4m3 storage
using bf16x8  = __attribute__((ext_vector_type(8))) __bf16;
using bf16x2  = __attribute__((ext_vector_type(2))) __bf16;
using floatx4 = __attribute__((ext_vector_type(4))) float;

__device__ inline int pack4_fp8(float4 a, float s) {
  int w = __builtin_amdgcn_cvt_pk_fp8_f32(a.x * s, a.y * s, 0, false);
  return __builtin_amdgcn_cvt_pk_fp8_f32(a.z * s, a.w * s, w, true);
}

// pack 8 scaled floats -> 8 e4m3 bytes
__device__ inline void store_fp8x8(f8_t* d, float4 a, float4 b, float s) {
  int2 v; v.x = pack4_fp8(a, s); v.y = pack4_fp8(b, s);
  *(int2*)d = v;
}

// async global->LDS, 16 B per lane. LDS dest = wave-uniform base + lane*16.
__device__ inline void gll16(const void* g, void* l) {
  __builtin_amdgcn_global_load_lds(
      (const __attribute__((address_space(1))) unsigned int*)g,
      (__attribute__((address_space(3))) unsigned int*)l, 16, 0, 0);
}

// ---------------------------------------------------------------------------
// Entity pool (device helper): user_n[b] = bf16 masked mean of
// ent_embs[ent_list[b,:cnt]]. One wave per b-row.
// ---------------------------------------------------------------------------
__device__ inline void pool_body(const float* __restrict__ ent,
                                 const int* __restrict__ ent_list,
                                 __bf16* __restrict__ user_n, int b) {
  const int lane = threadIdx.x & 63;
  int myidx = (lane < 50) ? ent_list[b * 50 + lane] : 0;
  unsigned long long m = __ballot(lane < 50 && myidx == SENTINEL);
  const int cnt = (m == 0) ? 50 : (int)__builtin_ctzll(m);

  float sx = 0.f, sy = 0.f;
  for (int l0 = 0; l0 < 50; l0 += 10) {
    if (l0 >= cnt) break;  // wave-uniform
    float2 e[10];
#pragma unroll
    for (int j = 0; j < 10; ++j) {
      int idx = __shfl(myidx, l0 + j);
      e[j] = *(const float2*)(ent + (size_t)idx * 128 + lane * 2);
    }
#pragma unroll
    for (int j = 0; j < 10; ++j) {
      if (l0 + j < cnt) { sx += e[j].x; sy += e[j].y; }
    }
  }
  float vx, vy;
  if (cnt == 0) {
    float2 e = *(const float2*)(ent + (size_t)SENTINEL * 128 + lane * 2);
    vx = e.x; vy = e.y;
  } else {
    float inv = 1.f / (float)cnt;
    vx = sx * inv; vy = sy * inv;
  }
  bf16x2 o; o[0] = (__bf16)vx; o[1] = (__bf16)vy;
  *(bf16x2*)(user_n + (size_t)b * 128 + lane * 2) = o;
}

// ---------------------------------------------------------------------------
// Dispatch 1 — prep: f32->fp8 convert of ctx (x1) and W1 (x16) only.
// ---------------------------------------------------------------------------
__global__ __launch_bounds__(256) void prep_kernel(
    const float* __restrict__ s0, f8_t* __restrict__ d0,
    const float* __restrict__ s1, f8_t* __restrict__ d1) {
  // sizes in 8-elem units: ctx 524288, W1 98304
  int g = blockIdx.x * 256 + threadIdx.x;
  const float* s; f8_t* d; int i; float sc;
  if (g < 524288)      { s = s0; d = d0; i = g;          sc = 1.f;  }
  else                 { s = s1; d = d1; i = g - 524288; sc = 16.f; }
  i *= 8;
  float4 a = *(const float4*)(s + i);
  float4 b = *(const float4*)(s + i + 4);
  store_fp8x8(d + i, a, b, sc);
}

// ---------------------------------------------------------------------------
// fp8 GEMM body: C = act( (A . W^T) * (1/16) ), A,W fp8 e4m3 row-major
// (K contiguous). Tile (WR*MT*16) x (WC*NT*16), BK = NS*32 slabs,
// 256 threads = 4 waves WR x WC. LDS rows 32 B unpadded (m97-style);
// gll16 chunks = 32 rows x 32 B. MFMA 16x16x32 fp8.
// R2-R4 ledger: >=2 blocks/CU required (1/CU costs +6.5us); beyond that,
// barrier count / tile shape / occupancy moves are all within +-1.2us.
// R6 lesson: NEVER feed MFMA from per-lane row-strided global loads — the
// 16-row x 512B-stride lane map fragments every load into ~16 transactions
// and stalls the whole kernel (flash went 27->66us). Always gll16-stage.
// ---------------------------------------------------------------------------
template <int WR, int WC, int MT, int NT, int RELU, bool OUT_BF16, int NS>
__device__ inline void gemm_body_f8(const f8_t* __restrict__ A,
                                    const f8_t* __restrict__ W,
                                    void* __restrict__ Cout,
                                    int M, int N, int K, int bn0, int bm0,
                                    char* lds) {
  constexpr int BM = WR * MT * 16;
  constexpr int BN = WC * NT * 16;
  auto As = (f8_t (*)[BM][32])lds;                        // As[s][r][k]
  auto Bs = (f8_t (*)[BN][32])(lds + (size_t)NS * BM * 32);
  const int tid  = threadIdx.x;
  const int w    = tid >> 6;
  const int lane = tid & 63;
  const int quad = lane >> 4;
  const int l16  = lane & 15;
  const int wr   = w / WC;
  const int wc   = w % WC;
  const int lrow = lane >> 1;        // 0..31 row within 1 KB chunk
  const int lcol = (lane & 1) * 16;  // fp8 col within 32-B slab row

  floatx4 acc[MT][NT];
#pragma unroll
  for (int mt = 0; mt < MT; ++mt)
#pragma unroll
    for (int nt = 0; nt < NT; ++nt) acc[mt][nt] = (floatx4){0.f, 0.f, 0.f, 0.f};

  constexpr int nAc = NS * (BM / 32);  // 1 KB chunks, slab-major
  constexpr int nBc = NS * (BN / 32);
  for (int k0 = 0; k0 < K; k0 += NS * 32) {
    __syncthreads();
#pragma unroll
    for (int c = w; c < nAc; c += 4) {
      int s = c / (BM / 32);
      int r = (c % (BM / 32)) * 32;
      gll16(A + (size_t)(bm0 + r + lrow) * K + k0 + s * 32 + lcol, &As[s][r][0]);
    }
#pragma unroll
    for (int c = w; c < nBc; c += 4) {
      int s = c / (BN / 32);
      int r = (c % (BN / 32)) * 32;
      gll16(W + (size_t)(bn0 + r + lrow) * K + k0 + s * 32 + lcol, &Bs[s][r][0]);
    }
    __syncthreads();
#pragma unroll
    for (int s = 0; s < NS; ++s) {
      long af[MT], bfr[NT];
#pragma unroll
      for (int mt = 0; mt < MT; ++mt)
        af[mt] = *(const long*)&As[s][wr * (MT * 16) + mt * 16 + l16][quad * 8];
#pragma unroll
      for (int nt = 0; nt < NT; ++nt)
        bfr[nt] = *(const long*)&Bs[s][wc * (NT * 16) + nt * 16 + l16][quad * 8];
#pragma unroll
      for (int mt = 0; mt < MT; ++mt)
#pragma unroll
        for (int nt = 0; nt < NT; ++nt)
          acc[mt][nt] = __builtin_amdgcn_mfma_f32_16x16x32_fp8_fp8(
              af[mt], bfr[nt], acc[mt][nt], 0, 0, 0);
    }
  }

  const float osc = 0.0625f;  // undo W x16
#pragma unroll
  for (int mt = 0; mt < MT; ++mt) {
    const int row0 = bm0 + wr * (MT * 16) + mt * 16 + quad * 4;
#pragma unroll
    for (int nt = 0; nt < NT; ++nt) {
      const int col = bn0 + wc * (NT * 16) + nt * 16 + l16;
#pragma unroll
      for (int r = 0; r < 4; ++r) {
        float v = acc[mt][nt][r] * osc;
        if (RELU) v = fmaxf(v, 0.f);
        if (OUT_BF16) {
          ((__bf16*)Cout)[(size_t)(row0 + r) * N + col] = (__bf16)v;
        } else {
          int p = __builtin_amdgcn_cvt_pk_fp8_f32(v, v, 0, false);
          ((f8_t*)Cout)[(size_t)(row0 + r) * N + col] = (f8_t)(p & 0xff);
        }
      }
    }
  }
}

// ---------------------------------------------------------------------------
// Dispatch 2 — gemm1 (fp8, 64x96, BK=128, blocks 0..511) fused with the
// entity pool (blocks 512..1535) and the W2/W3 converts (blocks 1536..1759).
// Races: none — nothing here reads user_n / x1b / W2b / W3b.
// ---------------------------------------------------------------------------
__global__ __launch_bounds__(256) void gemm1_pool(const f8_t* __restrict__ A,
                                                  const f8_t* __restrict__ W,
                                                  f8_t* __restrict__ C,
                                                  const float* __restrict__ ent,
                                                  const int* __restrict__ ent_list,
                                                  __bf16* __restrict__ user_n,
                                                  const float* __restrict__ s2,
                                                  f8_t* __restrict__ d2,
                                                  const float* __restrict__ s3,
                                                  f8_t* __restrict__ d3) {
  __shared__ char lds[20480];  // gemm: 4*(64+96)*32 = 20480
  const int bx = blockIdx.x;
  if (bx < 512) {
    gemm_body_f8<2, 2, 2, 3, 1, false, 4>(A, W, C, 4096, 768, 1024,
                                          (bx % 8) * 96, (bx / 8) * 64, lds);
    return;
  }
  if (bx < 1536) {
    pool_body(ent, ent_list, user_n, (bx - 512) * 4 + (threadIdx.x >> 6));
    return;
  }
  // W2: 49152 8-elem units, W3: 8192
  int g = (bx - 1536) * 256 + threadIdx.x;
  const float* s; f8_t* d; int i;
  if (g < 49152) { s = s2; d = d2; i = g; }
  else           { s = s3; d = d3; i = g - 49152; }
  i *= 8;
  float4 a = *(const float4*)(s + i);
  float4 b = *(const float4*)(s + i + 4);
  store_fp8x8(d + i, a, b, 16.f);
}

// ---------------------------------------------------------------------------
// Dispatch 3 — gemm2 (fp8, 64x64, BK=128, blocks 0..511) fused with the
// user_n -> user_t bf16 transpose (blocks 512..639).
// ---------------------------------------------------------------------------
__global__ __launch_bounds__(256) void gemm2_tr(const f8_t* __restrict__ A,
                                                const f8_t* __restrict__ W,
                                                f8_t* __restrict__ C,
                                                const __bf16* __restrict__ un,
                                                __bf16* __restrict__ ut) {
  __shared__ char lds[16384];  // gemm: 4*(64+64)*32 = 16384; tr: 9216
  const int bx = blockIdx.x;
  if (bx < 512) {
    gemm_body_f8<2, 2, 2, 2, 1, false, 4>(A, W, C, 4096, 512, 768,
                                          (bx % 8) * 64, (bx / 8) * 64, lds);
    return;
  }
  const int idx = bx - 512;             // 0..127
  const int r0 = (idx & 63) * 64;       // key rows
  const int c0 = (idx >> 6) * 64;       // dim cols
  auto T = (__bf16 (*)[72])lds;
  const int tid = threadIdx.x;
#pragma unroll
  for (int p = 0; p < 2; ++p) {
    int r = (tid >> 3) + p * 32;
    int c = (tid & 7) * 8;
    *(bf16x8*)&T[r][c] = *(const bf16x8*)(un + (size_t)(r0 + r) * 128 + c0 + c);
  }
  __syncthreads();
#pragma unroll
  for (int p = 0; p < 2; ++p) {
    int c = (tid >> 3) + p * 32;
    int r = (tid & 7) * 8;
    bf16x8 v;
#pragma unroll
    for (int j = 0; j < 8; ++j) v[j] = T[r + j][c];
    *(bf16x8*)(ut + (size_t)(c0 + c) * 4096 + r0 + r) = v;
  }
}

// ---------------------------------------------------------------------------
// Dispatch 4 — flash attention with FUSED Q-compute, R7 version.
// R6's direct per-lane global loads fragmented into ~16 txns each (flash
// 27->66us). R7: Q-phase is a gemm_body-style STAGED fp8 GEMM — gll16
// coalesced chunks of the X2 tile (128x512) and W3 (128x512) into LDS slabs
// (32 KB, aliasing the Un/Ut region; freed by barrier before Qlds write).
// Identical accumulation order -> bit-identical numerics vs gemm3.
// Q write-back to wave-private Qlds rows (no barrier), aq extraction, then
// the unchanged R5 main loop (T14 async-STAGE, setprio, elided last barriers).
// grid (32 q-tiles, 16 key-splits); LDS 54272 -> 2 blocks/CU.
// ---------------------------------------------------------------------------
__global__ __launch_bounds__(256) void flash_attn(const f8_t* __restrict__ X2,
                                                  const f8_t* __restrict__ W3,
                                                  const __bf16* __restrict__ Un_g,
                                                  const __bf16* __restrict__ Ut_g,
                                                  __bf16* __restrict__ O_part,
                                                  float* __restrict__ lp) {
  __shared__ char smem[54272];
  auto Un = (__bf16 (*)[136])smem;               // [64 key][136]  (17408 B)
  auto Ut = (__bf16 (*)[72])(smem + 17408);      // [128 d][72]    (18432 B)
  auto Ps = (__bf16 (*)[32][72])(smem + 35840);  // [4][32][72]    (18432 B)
  auto Qlds = (__bf16 (*)[136])smem;             // [128][136] aliases Un+Ut
  auto As = (f8_t (*)[128][32])smem;             // Q staging A, 16 KB
  auto Bs = (f8_t (*)[128][32])(smem + 16384);   // Q staging B, 16 KB
  const int tid  = threadIdx.x;
  const int w    = tid >> 6;
  const int lane = tid & 63;
  const int quad = lane >> 4;
  const int l16  = lane & 15;
  const int lrow = lane >> 1;        // staging: row within 1 KB chunk
  const int lcol = (lane & 1) * 16;  // staging: byte col within 32-B row
  const int qrow0 = blockIdx.x * 128;
  const int split = blockIdx.y;
  const float scale = 0.08838834764831845f;  // 1/sqrt(128)

  // T14 reg-staging lanes
  const int sr = tid >> 4, sc = (tid & 15) * 8;   // Un: rows sr+p*16, col sc
  const int td = tid >> 3, tk = (tid & 7) * 8;    // Ut: d td+p*32, key tk
  bf16x8 un_r[4], ut_r[4];

#define LD_CHUNK(key0)                                                         \
  do {                                                                         \
    _Pragma("unroll")                                                          \
    for (int p = 0; p < 4; ++p)                                                \
      un_r[p] = *(const bf16x8*)(Un_g + (size_t)((key0) + sr + p * 16) * 128 + sc); \
    _Pragma("unroll")                                                          \
    for (int p = 0; p < 4; ++p)                                                \
      ut_r[p] = *(const bf16x8*)(Ut_g + (size_t)(td + p * 32) * 4096 + (key0) + tk); \
  } while (0)

#define ST_CHUNK()                                                             \
  do {                                                                         \
    _Pragma("unroll")                                                          \
    for (int p = 0; p < 4; ++p) *(bf16x8*)&Un[sr + p * 16][sc] = un_r[p];      \
    _Pragma("unroll")                                                          \
    for (int p = 0; p < 4; ++p) *(bf16x8*)&Ut[td + p * 32][tk] = ut_r[p];      \
  } while (0)

  // ---- Q-phase: staged fp8 GEMM, Q[128][128] = (X2_tile . W3^T)/16 ----
  floatx4 qa[2][8];
#pragma unroll
  for (int mt = 0; mt < 2; ++mt)
#pragma unroll
    for (int nt = 0; nt < 8; ++nt) qa[mt][nt] = (floatx4){0.f, 0.f, 0.f, 0.f};

  for (int k0 = 0; k0 < 512; k0 += 128) {
    __syncthreads();
#pragma unroll
    for (int c = w; c < 16; c += 4) {   // A chunks: 4 slabs x 4 row-groups
      int s = c >> 2;
      int r = (c & 3) * 32;
      gll16(X2 + (size_t)(qrow0 + r + lrow) * 512 + k0 + s * 32 + lcol,
            &As[s][r][0]);
    }
#pragma unroll
    for (int c = w; c < 16; c += 4) {   // B chunks: all 128 W3 rows
      int s = c >> 2;
      int r = (c & 3) * 32;
      gll16(W3 + (size_t)(r + lrow) * 512 + k0 + s * 32 + lcol, &Bs[s][r][0]);
    }
    __syncthreads();
#pragma unroll
    for (int s = 0; s < 4; ++s) {
      long a0 = *(const long*)&As[s][w * 32 + l16][quad * 8];
      long a1 = *(const long*)&As[s][w * 32 + 16 + l16][quad * 8];
#pragma unroll
      for (int nt = 0; nt < 8; ++nt) {
        long bf = *(const long*)&Bs[s][nt * 16 + l16][quad * 8];
        qa[0][nt] = __builtin_amdgcn_mfma_f32_16x16x32_fp8_fp8(a0, bf, qa[0][nt], 0, 0, 0);
        qa[1][nt] = __builtin_amdgcn_mfma_f32_16x16x32_fp8_fp8(a1, bf, qa[1][nt], 0, 0, 0);
      }
    }
  }
  __syncthreads();  // all waves done with As/Bs; Qlds region writable

  LD_CHUNK(split * 256);  // first KV chunk in flight under Q write-back

  // C-layout write to wave-private Qlds rows, no barrier needed.
#pragma unroll
  for (int mt = 0; mt < 2; ++mt)
#pragma unroll
    for (int nt = 0; nt < 8; ++nt)
#pragma unroll
      for (int r = 0; r < 4; ++r)
        Qlds[w * 32 + mt * 16 + quad * 4 + r][nt * 16 + l16] =
            (__bf16)(qa[mt][nt][r] * 0.0625f);

  bf16x8 aq[2][4];
#pragma unroll
  for (int mt = 0; mt < 2; ++mt)
#pragma unroll
    for (int c = 0; c < 4; ++c)
      aq[mt][c] = *(const bf16x8*)&Qlds[w * 32 + mt * 16 + l16][c * 32 + quad * 8];

  floatx4 o[2][8];
#pragma unroll
  for (int mt = 0; mt < 2; ++mt)
#pragma unroll
    for (int t = 0; t < 8; ++t) o[mt][t] = (floatx4){0.f, 0.f, 0.f, 0.f};
  float lsum[2][4] = {{0.f, 0.f, 0.f, 0.f}, {0.f, 0.f, 0.f, 0.f}};

  __syncthreads();  // all waves done with Qlds; Un/Ut region reclaimable
  ST_CHUNK();       // implicit vmcnt wait on the prefetched KV regs
  __syncthreads();

  for (int chunk = 0; chunk < 4; ++chunk) {
    if (chunk < 3) LD_CHUNK(split * 256 + (chunk + 1) * 64);  // async prefetch

    // S = Q Uc^T for both m-tiles (bk read once), exp fp32, P -> LDS bf16.
#pragma unroll
    for (int t = 0; t < 4; ++t) {
      bf16x8 bk[4];
#pragma unroll
      for (int c = 0; c < 4; ++c)
        bk[c] = *(const bf16x8*)&Un[t * 16 + l16][c * 32 + quad * 8];
      floatx4 s0 = (floatx4){0.f, 0.f, 0.f, 0.f};
      floatx4 s1 = (floatx4){0.f, 0.f, 0.f, 0.f};
      __builtin_amdgcn_s_setprio(1);
#pragma unroll
      for (int c = 0; c < 4; ++c) {
        s0 = __builtin_amdgcn_mfma_f32_16x16x32_bf16(aq[0][c], bk[c], s0, 0, 0, 0);
        s1 = __builtin_amdgcn_mfma_f32_16x16x32_bf16(aq[1][c], bk[c], s1, 0, 0, 0);
      }
      __builtin_amdgcn_s_setprio(0);
#pragma unroll
      for (int r = 0; r < 4; ++r) {
        float p0 = __expf(s0[r] * scale);
        float p1 = __expf(s1[r] * scale);
        lsum[0][r] += p0;
        lsum[1][r] += p1;
        Ps[w][quad * 4 + r][t * 16 + l16] = (__bf16)p0;
        Ps[w][16 + quad * 4 + r][t * 16 + l16] = (__bf16)p1;
      }
    }
    // Ps wave-private: compiler lgkmcnt ordering suffices, no barrier.

    // O += P @ Uc (bv read once, used by both m-tiles)
#pragma unroll
    for (int c2 = 0; c2 < 2; ++c2) {
      bf16x8 ap0 = *(const bf16x8*)&Ps[w][l16][c2 * 32 + quad * 8];
      bf16x8 ap1 = *(const bf16x8*)&Ps[w][16 + l16][c2 * 32 + quad * 8];
      __builtin_amdgcn_s_setprio(1);
#pragma unroll
      for (int dt = 0; dt < 8; ++dt) {
        bf16x8 bv = *(const bf16x8*)&Ut[dt * 16 + l16][c2 * 32 + quad * 8];
        o[0][dt] = __builtin_amdgcn_mfma_f32_16x16x32_bf16(ap0, bv, o[0][dt], 0, 0, 0);
        o[1][dt] = __builtin_amdgcn_mfma_f32_16x16x32_bf16(ap1, bv, o[1][dt], 0, 0, 0);
      }
      __builtin_amdgcn_s_setprio(0);
    }

    if (chunk < 3) {
      __syncthreads();  // all waves done reading Un/Ut
      ST_CHUNK();       // implicit vmcnt wait on the prefetched regs
      __syncthreads();
    }
  }
#undef LD_CHUNK
#undef ST_CHUNK

  // Row sums: reduce over the 16 key-columns held across l16.
#pragma unroll
  for (int mt = 0; mt < 2; ++mt)
#pragma unroll
    for (int r = 0; r < 4; ++r) {
      float v = lsum[mt][r];
      v += __shfl_xor(v, 1);
      v += __shfl_xor(v, 2);
      v += __shfl_xor(v, 4);
      v += __shfl_xor(v, 8);
      lsum[mt][r] = v;
    }

  __bf16* Ob = O_part + (size_t)split * 524288;
#pragma unroll
  for (int mt = 0; mt < 2; ++mt) {
    const int row0 = qrow0 + w * 32 + mt * 16 + quad * 4;
#pragma unroll
    for (int dt = 0; dt < 8; ++dt) {
#pragma unroll
      for (int r = 0; r < 4; ++r) {
        Ob[(size_t)(row0 + r) * 128 + dt * 16 + l16] = (__bf16)o[mt][dt][r];
      }
    }
    if (l16 == 0) {
#pragma unroll
      for (int r = 0; r < 4; ++r) lp[(size_t)split * 4096 + row0 + r] = lsum[mt][r];
    }
  }
}

// ---------------------------------------------------------------------------
// Combine 16 key-splits: out = (sum_s O_s) / (sum_s lp[s][row]). 8 elems/thr.
// ---------------------------------------------------------------------------
__global__ __launch_bounds__(256) void combine_kernel(const __bf16* __restrict__ Op,
                                                      const float* __restrict__ lp,
                                                      float* __restrict__ out) {
  const int i = (blockIdx.x * 256 + threadIdx.x) * 8;  // 0 .. 524287 step 8
  const int row = i >> 7;
  float num[8] = {0.f, 0.f, 0.f, 0.f, 0.f, 0.f, 0.f, 0.f};
  float den = 0.f;
#pragma unroll
  for (int s = 0; s < 16; ++s) {
    bf16x8 v = *(const bf16x8*)(Op + (size_t)s * 524288 + i);
#pragma unroll
    for (int j = 0; j < 8; ++j) num[j] += (float)v[j];
    den += lp[(size_t)s * 4096 + row];
  }
  float inv = 1.f / den;
  float4 r0 = {num[0] * inv, num[1] * inv, num[2] * inv, num[3] * inv};
  float4 r1 = {num[4] * inv, num[5] * inv, num[6] * inv, num[7] * inv};
  *(float4*)(out + i) = r0;
  *(float4*)(out + i + 4) = r1;
}

extern "C" void kernel_launch(void* const* d_in, const int* in_sizes, int n_in,
                              void* d_out, int out_size, void* d_ws, size_t ws_size,
                              hipStream_t stream) {
  (void)in_sizes; (void)n_in; (void)out_size; (void)ws_size;
  const float* ctx      = (const float*)d_in[0];  // [4096,1024]
  const float* ent_embs = (const float*)d_in[1];  // [24636,128]
  const float* W1       = (const float*)d_in[2];  // [768,1024]
  const float* W2       = (const float*)d_in[3];  // [512,768]
  const float* W3       = (const float*)d_in[4];  // [128,512]
  const int*   ent_list = (const int*)d_in[5];    // [4096,50]
  float* out = (float*)d_out;

  // ws layout; peak use ~31 MB (ws is 256 MB).
  char* base = (char*)d_ws;
  __bf16* user_n = (__bf16*)(base);                       // 1 MB
  __bf16* user_t = (__bf16*)(base + (1ull << 20));        // 1 MB
  float*  lp     = (float*)(base + (3ull << 20));         // 256 KB [16][4096]
  f8_t*   ctxb   = (f8_t*)(base + (4ull << 20));          // 4 MB
  f8_t*   W1b    = (f8_t*)(base + (8ull << 20));          // 0.75 MB
  f8_t*   W2b    = (f8_t*)(base + 9175040ull);            // 8.75 MB, 384 KB
  f8_t*   W3b    = (f8_t*)(base + 9568256ull);            // 9.125 MB, 64 KB
  f8_t*   x1b    = (f8_t*)(base + (10ull << 20));         // 3 MB
  f8_t*   x2b    = (f8_t*)(base + (13ull << 20));         // 2 MB
  __bf16* O_part = (__bf16*)(base + (15ull << 20));       // 16 MB (bf16 x 16)

  // 5 dispatches. Critical path: prep -> gemm1 -> gemm2 -> flash(+Q) ->
  // combine; pool rides inside dispatch 2, tr inside dispatch 3.
  prep_kernel<<<2432, 256, 0, stream>>>(ctx, ctxb, W1, W1b);
  gemm1_pool<<<1760, 256, 0, stream>>>(ctxb, W1b, x1b, ent_embs, ent_list,
                                       user_n, W2, W2b, W3, W3b);
  gemm2_tr<<<640, 256, 0, stream>>>(x1b, W2b, x2b, user_n, user_t);
  flash_attn<<<dim3(32, 16), 256, 0, stream>>>(x2b, W3b, user_n, user_t,
                                               O_part, lp);
  combine_kernel<<<256, 256, 0, stream>>>(O_part, lp, out);
}

// Round 8
// 140.734 us; speedup vs baseline: 1.2772x; 1.0224x over previous
//
#include <hip/hip_runtime.h>
#include <hip/hip_bf16.h>

#define SENTINEL 24635

typedef unsigned char f8_t;  // OCP e4m3 storage
using bf16x8  = __attribute__((ext_vector_type(8))) __bf16;
using bf16x2  = __attribute__((ext_vector_type(2))) __bf16;
using floatx4 = __attribute__((ext_vector_type(4))) float;

__device__ inline int pack4_fp8(float4 a, float s) {
  int w = __builtin_amdgcn_cvt_pk_fp8_f32(a.x * s, a.y * s, 0, false);
  return __builtin_amdgcn_cvt_pk_fp8_f32(a.z * s, a.w * s, w, true);
}

// pack 8 scaled floats -> 8 e4m3 bytes
__device__ inline void store_fp8x8(f8_t* d, float4 a, float4 b, float s) {
  int2 v; v.x = pack4_fp8(a, s); v.y = pack4_fp8(b, s);
  *(int2*)d = v;
}

// async global->LDS, 16 B per lane. LDS dest = wave-uniform base + lane*16.
__device__ inline void gll16(const void* g, void* l) {
  __builtin_amdgcn_global_load_lds(
      (const __attribute__((address_space(1))) unsigned int*)g,
      (__attribute__((address_space(3))) unsigned int*)l, 16, 0, 0);
}

// ---------------------------------------------------------------------------
// Entity pool (device helper): user_n[b] = bf16 masked mean of
// ent_embs[ent_list[b,:cnt]]. One wave per b-row.
// ---------------------------------------------------------------------------
__device__ inline void pool_body(const float* __restrict__ ent,
                                 const int* __restrict__ ent_list,
                                 __bf16* __restrict__ user_n, int b) {
  const int lane = threadIdx.x & 63;
  int myidx = (lane < 50) ? ent_list[b * 50 + lane] : 0;
  unsigned long long m = __ballot(lane < 50 && myidx == SENTINEL);
  const int cnt = (m == 0) ? 50 : (int)__builtin_ctzll(m);

  float sx = 0.f, sy = 0.f;
  for (int l0 = 0; l0 < 50; l0 += 10) {
    if (l0 >= cnt) break;  // wave-uniform
    float2 e[10];
#pragma unroll
    for (int j = 0; j < 10; ++j) {
      int idx = __shfl(myidx, l0 + j);
      e[j] = *(const float2*)(ent + (size_t)idx * 128 + lane * 2);
    }
#pragma unroll
    for (int j = 0; j < 10; ++j) {
      if (l0 + j < cnt) { sx += e[j].x; sy += e[j].y; }
    }
  }
  float vx, vy;
  if (cnt == 0) {
    float2 e = *(const float2*)(ent + (size_t)SENTINEL * 128 + lane * 2);
    vx = e.x; vy = e.y;
  } else {
    float inv = 1.f / (float)cnt;
    vx = sx * inv; vy = sy * inv;
  }
  bf16x2 o; o[0] = (__bf16)vx; o[1] = (__bf16)vy;
  *(bf16x2*)(user_n + (size_t)b * 128 + lane * 2) = o;
}

// ---------------------------------------------------------------------------
// Dispatch 1 — prep: f32->fp8 convert of ctx (x1) and W1 (x16) only.
// ---------------------------------------------------------------------------
__global__ __launch_bounds__(256) void prep_kernel(
    const float* __restrict__ s0, f8_t* __restrict__ d0,
    const float* __restrict__ s1, f8_t* __restrict__ d1) {
  // sizes in 8-elem units: ctx 524288, W1 98304
  int g = blockIdx.x * 256 + threadIdx.x;
  const float* s; f8_t* d; int i; float sc;
  if (g < 524288)      { s = s0; d = d0; i = g;          sc = 1.f;  }
  else                 { s = s1; d = d1; i = g - 524288; sc = 16.f; }
  i *= 8;
  float4 a = *(const float4*)(s + i);
  float4 b = *(const float4*)(s + i + 4);
  store_fp8x8(d + i, a, b, sc);
}

// ---------------------------------------------------------------------------
// fp8 GEMM body: C = act( (A . W^T) * (1/16) ), A,W fp8 e4m3 row-major
// (K contiguous). Tile (WR*MT*16) x (WC*NT*16), BK = NS*32 slabs,
// 256 threads = 4 waves WR x WC. LDS rows 32 B unpadded (m97-style);
// gll16 chunks = 32 rows x 32 B. MFMA 16x16x32 fp8.
// Ledger: >=2 co-resident blocks/CU required (R2: 1/CU + thin filler =
// +6.5us); R8 tests big tile (128x96) WITH heavy filler (1024 pool blocks).
// R6 lesson: never feed MFMA from per-lane row-strided global loads.
// ---------------------------------------------------------------------------
template <int WR, int WC, int MT, int NT, int RELU, bool OUT_BF16, int NS>
__device__ inline void gemm_body_f8(const f8_t* __restrict__ A,
                                    const f8_t* __restrict__ W,
                                    void* __restrict__ Cout,
                                    int M, int N, int K, int bn0, int bm0,
                                    char* lds) {
  constexpr int BM = WR * MT * 16;
  constexpr int BN = WC * NT * 16;
  auto As = (f8_t (*)[BM][32])lds;                        // As[s][r][k]
  auto Bs = (f8_t (*)[BN][32])(lds + (size_t)NS * BM * 32);
  const int tid  = threadIdx.x;
  const int w    = tid >> 6;
  const int lane = tid & 63;
  const int quad = lane >> 4;
  const int l16  = lane & 15;
  const int wr   = w / WC;
  const int wc   = w % WC;
  const int lrow = lane >> 1;        // 0..31 row within 1 KB chunk
  const int lcol = (lane & 1) * 16;  // fp8 col within 32-B slab row

  floatx4 acc[MT][NT];
#pragma unroll
  for (int mt = 0; mt < MT; ++mt)
#pragma unroll
    for (int nt = 0; nt < NT; ++nt) acc[mt][nt] = (floatx4){0.f, 0.f, 0.f, 0.f};

  constexpr int nAc = NS * (BM / 32);  // 1 KB chunks, slab-major
  constexpr int nBc = NS * (BN / 32);
  for (int k0 = 0; k0 < K; k0 += NS * 32) {
    __syncthreads();
#pragma unroll
    for (int c = w; c < nAc; c += 4) {
      int s = c / (BM / 32);
      int r = (c % (BM / 32)) * 32;
      gll16(A + (size_t)(bm0 + r + lrow) * K + k0 + s * 32 + lcol, &As[s][r][0]);
    }
#pragma unroll
    for (int c = w; c < nBc; c += 4) {
      int s = c / (BN / 32);
      int r = (c % (BN / 32)) * 32;
      gll16(W + (size_t)(bn0 + r + lrow) * K + k0 + s * 32 + lcol, &Bs[s][r][0]);
    }
    __syncthreads();
#pragma unroll
    for (int s = 0; s < NS; ++s) {
      long af[MT], bfr[NT];
#pragma unroll
      for (int mt = 0; mt < MT; ++mt)
        af[mt] = *(const long*)&As[s][wr * (MT * 16) + mt * 16 + l16][quad * 8];
#pragma unroll
      for (int nt = 0; nt < NT; ++nt)
        bfr[nt] = *(const long*)&Bs[s][wc * (NT * 16) + nt * 16 + l16][quad * 8];
#pragma unroll
      for (int mt = 0; mt < MT; ++mt)
#pragma unroll
        for (int nt = 0; nt < NT; ++nt)
          acc[mt][nt] = __builtin_amdgcn_mfma_f32_16x16x32_fp8_fp8(
              af[mt], bfr[nt], acc[mt][nt], 0, 0, 0);
    }
  }

  const float osc = 0.0625f;  // undo W x16
#pragma unroll
  for (int mt = 0; mt < MT; ++mt) {
    const int row0 = bm0 + wr * (MT * 16) + mt * 16 + quad * 4;
#pragma unroll
    for (int nt = 0; nt < NT; ++nt) {
      const int col = bn0 + wc * (NT * 16) + nt * 16 + l16;
#pragma unroll
      for (int r = 0; r < 4; ++r) {
        float v = acc[mt][nt][r] * osc;
        if (RELU) v = fmaxf(v, 0.f);
        if (OUT_BF16) {
          ((__bf16*)Cout)[(size_t)(row0 + r) * N + col] = (__bf16)v;
        } else {
          int p = __builtin_amdgcn_cvt_pk_fp8_f32(v, v, 0, false);
          ((f8_t*)Cout)[(size_t)(row0 + r) * N + col] = (f8_t)(p & 0xff);
        }
      }
    }
  }
}

template <int WR, int WC, int MT, int NT, int RELU, bool OUT_BF16, int NS>
__global__ __launch_bounds__(256) void gemm_f8(const f8_t* __restrict__ A,
                                               const f8_t* __restrict__ W,
                                               void* __restrict__ C,
                                               int M, int N, int K) {
  __shared__ char lds[(size_t)NS * ((WR * MT * 16) + (WC * NT * 16)) * 32];
  gemm_body_f8<WR, WC, MT, NT, RELU, OUT_BF16, NS>(
      A, W, C, M, N, K, blockIdx.x * (WC * NT * 16), blockIdx.y * (WR * MT * 16),
      lds);
}

// ---------------------------------------------------------------------------
// Dispatch 2 — gemm1 (fp8, 128x96 tiles, BK=128, blocks 0..255) fused with
// the entity pool (blocks 256..1279 — heavy co-resident filler covering the
// gemm's barrier drains) and the W2/W3 converts (blocks 1280..1503).
// Races: none — nothing here reads user_n / x1b / W2b / W3b.
// ---------------------------------------------------------------------------
__global__ __launch_bounds__(256) void gemm1_pool(const f8_t* __restrict__ A,
                                                  const f8_t* __restrict__ W,
                                                  f8_t* __restrict__ C,
                                                  const float* __restrict__ ent,
                                                  const int* __restrict__ ent_list,
                                                  __bf16* __restrict__ user_n,
                                                  const float* __restrict__ s2,
                                                  f8_t* __restrict__ d2,
                                                  const float* __restrict__ s3,
                                                  f8_t* __restrict__ d3) {
  __shared__ char lds[28672];  // gemm: 4*(128+96)*32 = 28672 -> 5 blocks/CU cap
  const int bx = blockIdx.x;
  if (bx < 256) {
    gemm_body_f8<2, 2, 4, 3, 1, false, 4>(A, W, C, 4096, 768, 1024,
                                          (bx % 8) * 96, (bx / 8) * 128, lds);
    return;
  }
  if (bx < 1280) {
    pool_body(ent, ent_list, user_n, (bx - 256) * 4 + (threadIdx.x >> 6));
    return;
  }
  // W2: 49152 8-elem units, W3: 8192
  int g = (bx - 1280) * 256 + threadIdx.x;
  const float* s; f8_t* d; int i;
  if (g < 49152) { s = s2; d = d2; i = g; }
  else           { s = s3; d = d3; i = g - 49152; }
  i *= 8;
  float4 a = *(const float4*)(s + i);
  float4 b = *(const float4*)(s + i + 4);
  store_fp8x8(d + i, a, b, 16.f);
}

// ---------------------------------------------------------------------------
// Dispatch 3 — gemm2 (fp8, 64x64, BK=128, blocks 0..511) fused with the
// user_n -> user_t bf16 transpose (blocks 512..639).
// ---------------------------------------------------------------------------
__global__ __launch_bounds__(256) void gemm2_tr(const f8_t* __restrict__ A,
                                                const f8_t* __restrict__ W,
                                                f8_t* __restrict__ C,
                                                const __bf16* __restrict__ un,
                                                __bf16* __restrict__ ut) {
  __shared__ char lds[16384];  // gemm: 4*(64+64)*32 = 16384; tr: 9216
  const int bx = blockIdx.x;
  if (bx < 512) {
    gemm_body_f8<2, 2, 2, 2, 1, false, 4>(A, W, C, 4096, 512, 768,
                                          (bx % 8) * 64, (bx / 8) * 64, lds);
    return;
  }
  const int idx = bx - 512;             // 0..127
  const int r0 = (idx & 63) * 64;       // key rows
  const int c0 = (idx >> 6) * 64;       // dim cols
  auto T = (__bf16 (*)[72])lds;
  const int tid = threadIdx.x;
#pragma unroll
  for (int p = 0; p < 2; ++p) {
    int r = (tid >> 3) + p * 32;
    int c = (tid & 7) * 8;
    *(bf16x8*)&T[r][c] = *(const bf16x8*)(un + (size_t)(r0 + r) * 128 + c0 + c);
  }
  __syncthreads();
#pragma unroll
  for (int p = 0; p < 2; ++p) {
    int c = (tid >> 3) + p * 32;
    int r = (tid & 7) * 8;
    bf16x8 v;
#pragma unroll
    for (int j = 0; j < 8; ++j) v[j] = T[r + j][c];
    *(bf16x8*)(ut + (size_t)(c0 + c) * 4096 + r0 + r) = v;
  }
}

// ---------------------------------------------------------------------------
// Dispatch 5 — flash attention (bf16), R5 form (gemm3 separate again; R7's
// per-block Q-fusion measured +2.8us net vs this). BM=128, LDS-staged,
// no max-subtraction (|scores| ~ 1e-2). grid (32 q-tiles, 16 key-splits);
// 4 chunks of 64 keys per split; LDS 54272.
// NO fences/atomics (R11: device-scope fences cost ~60 us here).
// T14 async-STAGE + s_setprio; last-chunk barriers elided.
// ---------------------------------------------------------------------------
__global__ __launch_bounds__(256) void flash_attn(const __bf16* __restrict__ Q,
                                                  const __bf16* __restrict__ Un_g,
                                                  const __bf16* __restrict__ Ut_g,
                                                  __bf16* __restrict__ O_part,
                                                  float* __restrict__ lp) {
  __shared__ __bf16 Un[64][136];    // [key][d]   stride 272 B (2-way banks)
  __shared__ __bf16 Ut[128][72];    // [d][key]   stride 144 B
  __shared__ __bf16 Ps[4][32][72];  // per-wave P [qrow 0..31][key], wave-private
  const int tid  = threadIdx.x;
  const int w    = tid >> 6;
  const int lane = tid & 63;
  const int quad = lane >> 4;
  const int l16  = lane & 15;
  const int qrow0 = blockIdx.x * 128;
  const int split = blockIdx.y;
  const float scale = 0.08838834764831845f;  // 1/sqrt(128)

  bf16x8 aq[2][4];
#pragma unroll
  for (int mt = 0; mt < 2; ++mt)
#pragma unroll
    for (int c = 0; c < 4; ++c)
      aq[mt][c] = *(const bf16x8*)(Q + (size_t)(qrow0 + w * 32 + mt * 16 + l16) * 128 +
                                   c * 32 + quad * 8);

  floatx4 o[2][8];
#pragma unroll
  for (int mt = 0; mt < 2; ++mt)
#pragma unroll
    for (int t = 0; t < 8; ++t) o[mt][t] = (floatx4){0.f, 0.f, 0.f, 0.f};
  float lsum[2][4] = {{0.f, 0.f, 0.f, 0.f}, {0.f, 0.f, 0.f, 0.f}};

  // T14 reg-staging lanes (same footprint as the old direct staging loops)
  const int sr = tid >> 4, sc = (tid & 15) * 8;   // Un: rows sr+p*16, col sc
  const int td = tid >> 3, tk = (tid & 7) * 8;    // Ut: d td+p*32, key tk
  bf16x8 un_r[4], ut_r[4];

#define LD_CHUNK(key0)                                                         \
  do {                                                                         \
    _Pragma("unroll")                                                          \
    for (int p = 0; p < 4; ++p)                                                \
      un_r[p] = *(const bf16x8*)(Un_g + (size_t)((key0) + sr + p * 16) * 128 + sc); \
    _Pragma("unroll")                                                          \
    for (int p = 0; p < 4; ++p)                                                \
      ut_r[p] = *(const bf16x8*)(Ut_g + (size_t)(td + p * 32) * 4096 + (key0) + tk); \
  } while (0)

#define ST_CHUNK()                                                             \
  do {                                                                         \
    _Pragma("unroll")                                                          \
    for (int p = 0; p < 4; ++p) *(bf16x8*)&Un[sr + p * 16][sc] = un_r[p];      \
    _Pragma("unroll")                                                          \
    for (int p = 0; p < 4; ++p) *(bf16x8*)&Ut[td + p * 32][tk] = ut_r[p];      \
  } while (0)

  LD_CHUNK(split * 256);
  ST_CHUNK();
  __syncthreads();

  for (int chunk = 0; chunk < 4; ++chunk) {
    if (chunk < 3) LD_CHUNK(split * 256 + (chunk + 1) * 64);  // async prefetch

    // S = Q Uc^T for both m-tiles (bk read once), exp fp32, P -> LDS bf16.
#pragma unroll
    for (int t = 0; t < 4; ++t) {
      bf16x8 bk[4];
#pragma unroll
      for (int c = 0; c < 4; ++c)
        bk[c] = *(const bf16x8*)&Un[t * 16 + l16][c * 32 + quad * 8];
      floatx4 s0 = (floatx4){0.f, 0.f, 0.f, 0.f};
      floatx4 s1 = (floatx4){0.f, 0.f, 0.f, 0.f};
      __builtin_amdgcn_s_setprio(1);
#pragma unroll
      for (int c = 0; c < 4; ++c) {
        s0 = __builtin_amdgcn_mfma_f32_16x16x32_bf16(aq[0][c], bk[c], s0, 0, 0, 0);
        s1 = __builtin_amdgcn_mfma_f32_16x16x32_bf16(aq[1][c], bk[c], s1, 0, 0, 0);
      }
      __builtin_amdgcn_s_setprio(0);
#pragma unroll
      for (int r = 0; r < 4; ++r) {
        float p0 = __expf(s0[r] * scale);
        float p1 = __expf(s1[r] * scale);
        lsum[0][r] += p0;
        lsum[1][r] += p1;
        Ps[w][quad * 4 + r][t * 16 + l16] = (__bf16)p0;
        Ps[w][16 + quad * 4 + r][t * 16 + l16] = (__bf16)p1;
      }
    }
    // Ps wave-private: compiler lgkmcnt ordering suffices, no barrier.

    // O += P @ Uc (bv read once, used by both m-tiles)
#pragma unroll
    for (int c2 = 0; c2 < 2; ++c2) {
      bf16x8 ap0 = *(const bf16x8*)&Ps[w][l16][c2 * 32 + quad * 8];
      bf16x8 ap1 = *(const bf16x8*)&Ps[w][16 + l16][c2 * 32 + quad * 8];
      __builtin_amdgcn_s_setprio(1);
#pragma unroll
      for (int dt = 0; dt < 8; ++dt) {
        bf16x8 bv = *(const bf16x8*)&Ut[dt * 16 + l16][c2 * 32 + quad * 8];
        o[0][dt] = __builtin_amdgcn_mfma_f32_16x16x32_bf16(ap0, bv, o[0][dt], 0, 0, 0);
        o[1][dt] = __builtin_amdgcn_mfma_f32_16x16x32_bf16(ap1, bv, o[1][dt], 0, 0, 0);
      }
      __builtin_amdgcn_s_setprio(0);
    }

    if (chunk < 3) {
      __syncthreads();  // all waves done reading Un/Ut
      ST_CHUNK();       // implicit vmcnt wait on the prefetched regs
      __syncthreads();
    }
  }
#undef LD_CHUNK
#undef ST_CHUNK

  // Row sums: reduce over the 16 key-columns held across l16.
#pragma unroll
  for (int mt = 0; mt < 2; ++mt)
#pragma unroll
    for (int r = 0; r < 4; ++r) {
      float v = lsum[mt][r];
      v += __shfl_xor(v, 1);
      v += __shfl_xor(v, 2);
      v += __shfl_xor(v, 4);
      v += __shfl_xor(v, 8);
      lsum[mt][r] = v;
    }

  __bf16* Ob = O_part + (size_t)split * 524288;
#pragma unroll
  for (int mt = 0; mt < 2; ++mt) {
    const int row0 = qrow0 + w * 32 + mt * 16 + quad * 4;
#pragma unroll
    for (int dt = 0; dt < 8; ++dt) {
#pragma unroll
      for (int r = 0; r < 4; ++r) {
        Ob[(size_t)(row0 + r) * 128 + dt * 16 + l16] = (__bf16)o[mt][dt][r];
      }
    }
    if (l16 == 0) {
#pragma unroll
      for (int r = 0; r < 4; ++r) lp[(size_t)split * 4096 + row0 + r] = lsum[mt][r];
    }
  }
}

// ---------------------------------------------------------------------------
// Combine 16 key-splits: out = (sum_s O_s) / (sum_s lp[s][row]). 8 elems/thr.
// ---------------------------------------------------------------------------
__global__ __launch_bounds__(256) void combine_kernel(const __bf16* __restrict__ Op,
                                                      const float* __restrict__ lp,
                                                      float* __restrict__ out) {
  const int i = (blockIdx.x * 256 + threadIdx.x) * 8;  // 0 .. 524287 step 8
  const int row = i >> 7;
  float num[8] = {0.f, 0.f, 0.f, 0.f, 0.f, 0.f, 0.f, 0.f};
  float den = 0.f;
#pragma unroll
  for (int s = 0; s < 16; ++s) {
    bf16x8 v = *(const bf16x8*)(Op + (size_t)s * 524288 + i);
#pragma unroll
    for (int j = 0; j < 8; ++j) num[j] += (float)v[j];
    den += lp[(size_t)s * 4096 + row];
  }
  float inv = 1.f / den;
  float4 r0 = {num[0] * inv, num[1] * inv, num[2] * inv, num[3] * inv};
  float4 r1 = {num[4] * inv, num[5] * inv, num[6] * inv, num[7] * inv};
  *(float4*)(out + i) = r0;
  *(float4*)(out + i + 4) = r1;
}

extern "C" void kernel_launch(void* const* d_in, const int* in_sizes, int n_in,
                              void* d_out, int out_size, void* d_ws, size_t ws_size,
                              hipStream_t stream) {
  (void)in_sizes; (void)n_in; (void)out_size; (void)ws_size;
  const float* ctx      = (const float*)d_in[0];  // [4096,1024]
  const float* ent_embs = (const float*)d_in[1];  // [24636,128]
  const float* W1       = (const float*)d_in[2];  // [768,1024]
  const float* W2       = (const float*)d_in[3];  // [512,768]
  const float* W3       = (const float*)d_in[4];  // [128,512]
  const int*   ent_list = (const int*)d_in[5];    // [4096,50]
  float* out = (float*)d_out;

  // ws layout; peak use ~31 MB (ws is 256 MB).
  char* base = (char*)d_ws;
  __bf16* user_n = (__bf16*)(base);                       // 1 MB
  __bf16* user_t = (__bf16*)(base + (1ull << 20));        // 1 MB
  __bf16* qb     = (__bf16*)(base + (2ull << 20));        // 1 MB
  float*  lp     = (float*)(base + (3ull << 20));         // 256 KB [16][4096]
  f8_t*   ctxb   = (f8_t*)(base + (4ull << 20));          // 4 MB
  f8_t*   W1b    = (f8_t*)(base + (8ull << 20));          // 0.75 MB
  f8_t*   W2b    = (f8_t*)(base + 9175040ull);            // 8.75 MB, 384 KB
  f8_t*   W3b    = (f8_t*)(base + 9568256ull);            // 9.125 MB, 64 KB
  f8_t*   x1b    = (f8_t*)(base + (10ull << 20));         // 3 MB
  f8_t*   x2b    = (f8_t*)(base + (13ull << 20));         // 2 MB
  __bf16* O_part = (__bf16*)(base + (15ull << 20));       // 16 MB (bf16 x 16)

  // 6 dispatches. Critical path: prep -> gemm1 -> gemm2 -> gemm3 -> flash
  // -> combine; pool rides inside dispatch 2, tr inside dispatch 3.
  prep_kernel<<<2432, 256, 0, stream>>>(ctx, ctxb, W1, W1b);
  gemm1_pool<<<1504, 256, 0, stream>>>(ctxb, W1b, x1b, ent_embs, ent_list,
                                       user_n, W2, W2b, W3, W3b);
  gemm2_tr<<<640, 256, 0, stream>>>(x1b, W2b, x2b, user_n, user_t);
  gemm_f8<2, 2, 1, 1, 0, true, 4><<<dim3(4, 128), 256, 0, stream>>>(
      x2b, W3b, qb, 4096, 128, 512);
  flash_attn<<<dim3(32, 16), 256, 0, stream>>>(qb, user_n, user_t, O_part, lp);
  combine_kernel<<<256, 256, 0, stream>>>(O_part, lp, out);
}

// Round 9
// 140.644 us; speedup vs baseline: 1.2780x; 1.0006x over previous
//
#include <hip/hip_runtime.h>
#include <hip/hip_bf16.h>

#define SENTINEL 24635

typedef unsigned char f8_t;  // OCP e4m3 storage
using bf16x8  = __attribute__((ext_vector_type(8))) __bf16;
using bf16x2  = __attribute__((ext_vector_type(2))) __bf16;
using floatx4 = __attribute__((ext_vector_type(4))) float;

__device__ inline int pack4_fp8(float4 a, float s) {
  int w = __builtin_amdgcn_cvt_pk_fp8_f32(a.x * s, a.y * s, 0, false);
  return __builtin_amdgcn_cvt_pk_fp8_f32(a.z * s, a.w * s, w, true);
}

// pack 8 scaled floats -> 8 e4m3 bytes
__device__ inline void store_fp8x8(f8_t* d, float4 a, float4 b, float s) {
  int2 v; v.x = pack4_fp8(a, s); v.y = pack4_fp8(b, s);
  *(int2*)d = v;
}

// async global->LDS, 16 B per lane. LDS dest = wave-uniform base + lane*16.
__device__ inline void gll16(const void* g, void* l) {
  __builtin_amdgcn_global_load_lds(
      (const __attribute__((address_space(1))) unsigned int*)g,
      (__attribute__((address_space(3))) unsigned int*)l, 16, 0, 0);
}

// ---------------------------------------------------------------------------
// Entity pool (device helper): user_n[b] = bf16 masked mean of
// ent_embs[ent_list[b,:cnt]]. One wave per b-row.
// ---------------------------------------------------------------------------
__device__ inline void pool_body(const float* __restrict__ ent,
                                 const int* __restrict__ ent_list,
                                 __bf16* __restrict__ user_n, int b) {
  const int lane = threadIdx.x & 63;
  int myidx = (lane < 50) ? ent_list[b * 50 + lane] : 0;
  unsigned long long m = __ballot(lane < 50 && myidx == SENTINEL);
  const int cnt = (m == 0) ? 50 : (int)__builtin_ctzll(m);

  float sx = 0.f, sy = 0.f;
  for (int l0 = 0; l0 < 50; l0 += 10) {
    if (l0 >= cnt) break;  // wave-uniform
    float2 e[10];
#pragma unroll
    for (int j = 0; j < 10; ++j) {
      int idx = __shfl(myidx, l0 + j);
      e[j] = *(const float2*)(ent + (size_t)idx * 128 + lane * 2);
    }
#pragma unroll
    for (int j = 0; j < 10; ++j) {
      if (l0 + j < cnt) { sx += e[j].x; sy += e[j].y; }
    }
  }
  float vx, vy;
  if (cnt == 0) {
    float2 e = *(const float2*)(ent + (size_t)SENTINEL * 128 + lane * 2);
    vx = e.x; vy = e.y;
  } else {
    float inv = 1.f / (float)cnt;
    vx = sx * inv; vy = sy * inv;
  }
  bf16x2 o; o[0] = (__bf16)vx; o[1] = (__bf16)vy;
  *(bf16x2*)(user_n + (size_t)b * 128 + lane * 2) = o;
}

// ---------------------------------------------------------------------------
// Dispatch 1 — prep: f32->fp8 convert of ctx (x1) and W1 (x16) only.
// ---------------------------------------------------------------------------
__global__ __launch_bounds__(256) void prep_kernel(
    const float* __restrict__ s0, f8_t* __restrict__ d0,
    const float* __restrict__ s1, f8_t* __restrict__ d1) {
  // sizes in 8-elem units: ctx 524288, W1 98304
  int g = blockIdx.x * 256 + threadIdx.x;
  const float* s; f8_t* d; int i; float sc;
  if (g < 524288)      { s = s0; d = d0; i = g;          sc = 1.f;  }
  else                 { s = s1; d = d1; i = g - 524288; sc = 16.f; }
  i *= 8;
  float4 a = *(const float4*)(s + i);
  float4 b = *(const float4*)(s + i + 4);
  store_fp8x8(d + i, a, b, sc);
}

// ---------------------------------------------------------------------------
// fp8 GEMM body: C = act( (A . W^T) * (1/16) ), A,W fp8 e4m3 row-major
// (K contiguous). Tile (WR*MT*16) x (WC*NT*16), BK = NS*32 slabs,
// 256 threads = 4 waves WR x WC. LDS rows 32 B unpadded (m97-style);
// gll16 chunks = 32 rows x 32 B. MFMA 16x16x32 fp8.
// Ledger: >=2 co-resident blocks/CU required (R2); 128x96 + heavy filler =
// best measured (R8). R6 lesson: never feed MFMA from per-lane row-strided
// global loads — always gll16-stage.
// ---------------------------------------------------------------------------
template <int WR, int WC, int MT, int NT, int RELU, bool OUT_BF16, int NS>
__device__ inline void gemm_body_f8(const f8_t* __restrict__ A,
                                    const f8_t* __restrict__ W,
                                    void* __restrict__ Cout,
                                    int M, int N, int K, int bn0, int bm0,
                                    char* lds) {
  constexpr int BM = WR * MT * 16;
  constexpr int BN = WC * NT * 16;
  auto As = (f8_t (*)[BM][32])lds;                        // As[s][r][k]
  auto Bs = (f8_t (*)[BN][32])(lds + (size_t)NS * BM * 32);
  const int tid  = threadIdx.x;
  const int w    = tid >> 6;
  const int lane = tid & 63;
  const int quad = lane >> 4;
  const int l16  = lane & 15;
  const int wr   = w / WC;
  const int wc   = w % WC;
  const int lrow = lane >> 1;        // 0..31 row within 1 KB chunk
  const int lcol = (lane & 1) * 16;  // fp8 col within 32-B slab row

  floatx4 acc[MT][NT];
#pragma unroll
  for (int mt = 0; mt < MT; ++mt)
#pragma unroll
    for (int nt = 0; nt < NT; ++nt) acc[mt][nt] = (floatx4){0.f, 0.f, 0.f, 0.f};

  constexpr int nAc = NS * (BM / 32);  // 1 KB chunks, slab-major
  constexpr int nBc = NS * (BN / 32);
  for (int k0 = 0; k0 < K; k0 += NS * 32) {
    __syncthreads();
#pragma unroll
    for (int c = w; c < nAc; c += 4) {
      int s = c / (BM / 32);
      int r = (c % (BM / 32)) * 32;
      gll16(A + (size_t)(bm0 + r + lrow) * K + k0 + s * 32 + lcol, &As[s][r][0]);
    }
#pragma unroll
    for (int c = w; c < nBc; c += 4) {
      int s = c / (BN / 32);
      int r = (c % (BN / 32)) * 32;
      gll16(W + (size_t)(bn0 + r + lrow) * K + k0 + s * 32 + lcol, &Bs[s][r][0]);
    }
    __syncthreads();
#pragma unroll
    for (int s = 0; s < NS; ++s) {
      long af[MT], bfr[NT];
#pragma unroll
      for (int mt = 0; mt < MT; ++mt)
        af[mt] = *(const long*)&As[s][wr * (MT * 16) + mt * 16 + l16][quad * 8];
#pragma unroll
      for (int nt = 0; nt < NT; ++nt)
        bfr[nt] = *(const long*)&Bs[s][wc * (NT * 16) + nt * 16 + l16][quad * 8];
#pragma unroll
      for (int mt = 0; mt < MT; ++mt)
#pragma unroll
        for (int nt = 0; nt < NT; ++nt)
          acc[mt][nt] = __builtin_amdgcn_mfma_f32_16x16x32_fp8_fp8(
              af[mt], bfr[nt], acc[mt][nt], 0, 0, 0);
    }
  }

  const float osc = 0.0625f;  // undo W x16
#pragma unroll
  for (int mt = 0; mt < MT; ++mt) {
    const int row0 = bm0 + wr * (MT * 16) + mt * 16 + quad * 4;
#pragma unroll
    for (int nt = 0; nt < NT; ++nt) {
      const int col = bn0 + wc * (NT * 16) + nt * 16 + l16;
#pragma unroll
      for (int r = 0; r < 4; ++r) {
        float v = acc[mt][nt][r] * osc;
        if (RELU) v = fmaxf(v, 0.f);
        if (OUT_BF16) {
          ((__bf16*)Cout)[(size_t)(row0 + r) * N + col] = (__bf16)v;
        } else {
          int p = __builtin_amdgcn_cvt_pk_fp8_f32(v, v, 0, false);
          ((f8_t*)Cout)[(size_t)(row0 + r) * N + col] = (f8_t)(p & 0xff);
        }
      }
    }
  }
}

template <int WR, int WC, int MT, int NT, int RELU, bool OUT_BF16, int NS>
__global__ __launch_bounds__(256) void gemm_f8(const f8_t* __restrict__ A,
                                               const f8_t* __restrict__ W,
                                               void* __restrict__ C,
                                               int M, int N, int K) {
  __shared__ char lds[(size_t)NS * ((WR * MT * 16) + (WC * NT * 16)) * 32];
  gemm_body_f8<WR, WC, MT, NT, RELU, OUT_BF16, NS>(
      A, W, C, M, N, K, blockIdx.x * (WC * NT * 16), blockIdx.y * (WR * MT * 16),
      lds);
}

// ---------------------------------------------------------------------------
// Dispatch 2 — gemm1 (fp8, 128x96 tiles, BK=128, blocks 0..255) fused with
// the entity pool (blocks 256..1279 — heavy co-resident filler covering the
// gemm's barrier drains) and the W2/W3 converts (blocks 1280..1503).
// Races: none — nothing here reads user_n / x1b / W2b / W3b.
// ---------------------------------------------------------------------------
__global__ __launch_bounds__(256) void gemm1_pool(const f8_t* __restrict__ A,
                                                  const f8_t* __restrict__ W,
                                                  f8_t* __restrict__ C,
                                                  const float* __restrict__ ent,
                                                  const int* __restrict__ ent_list,
                                                  __bf16* __restrict__ user_n,
                                                  const float* __restrict__ s2,
                                                  f8_t* __restrict__ d2,
                                                  const float* __restrict__ s3,
                                                  f8_t* __restrict__ d3) {
  __shared__ char lds[28672];  // gemm: 4*(128+96)*32 = 28672 -> 5 blocks/CU cap
  const int bx = blockIdx.x;
  if (bx < 256) {
    gemm_body_f8<2, 2, 4, 3, 1, false, 4>(A, W, C, 4096, 768, 1024,
                                          (bx % 8) * 96, (bx / 8) * 128, lds);
    return;
  }
  if (bx < 1280) {
    pool_body(ent, ent_list, user_n, (bx - 256) * 4 + (threadIdx.x >> 6));
    return;
  }
  // W2: 49152 8-elem units, W3: 8192
  int g = (bx - 1280) * 256 + threadIdx.x;
  const float* s; f8_t* d; int i;
  if (g < 49152) { s = s2; d = d2; i = g; }
  else           { s = s3; d = d3; i = g - 49152; }
  i *= 8;
  float4 a = *(const float4*)(s + i);
  float4 b = *(const float4*)(s + i + 4);
  store_fp8x8(d + i, a, b, 16.f);
}

// ---------------------------------------------------------------------------
// Dispatch 3 — gemm2 (fp8, 64x64, BK=128, blocks 0..511) fused with the
// user_n -> user_t bf16 transpose (blocks 512..639).
// ---------------------------------------------------------------------------
__global__ __launch_bounds__(256) void gemm2_tr(const f8_t* __restrict__ A,
                                                const f8_t* __restrict__ W,
                                                f8_t* __restrict__ C,
                                                const __bf16* __restrict__ un,
                                                __bf16* __restrict__ ut) {
  __shared__ char lds[16384];  // gemm: 4*(64+64)*32 = 16384; tr: 9216
  const int bx = blockIdx.x;
  if (bx < 512) {
    gemm_body_f8<2, 2, 2, 2, 1, false, 4>(A, W, C, 4096, 512, 768,
                                          (bx % 8) * 64, (bx / 8) * 64, lds);
    return;
  }
  const int idx = bx - 512;             // 0..127
  const int r0 = (idx & 63) * 64;       // key rows
  const int c0 = (idx >> 6) * 64;       // dim cols
  auto T = (__bf16 (*)[72])lds;
  const int tid = threadIdx.x;
#pragma unroll
  for (int p = 0; p < 2; ++p) {
    int r = (tid >> 3) + p * 32;
    int c = (tid & 7) * 8;
    *(bf16x8*)&T[r][c] = *(const bf16x8*)(un + (size_t)(r0 + r) * 128 + c0 + c);
  }
  __syncthreads();
#pragma unroll
  for (int p = 0; p < 2; ++p) {
    int c = (tid >> 3) + p * 32;
    int r = (tid & 7) * 8;
    bf16x8 v;
#pragma unroll
    for (int j = 0; j < 8; ++j) v[j] = T[r + j][c];
    *(bf16x8*)(ut + (size_t)(c0 + c) * 4096 + r0 + r) = v;
  }
}

// ---------------------------------------------------------------------------
// Dispatch 5 — flash attention (bf16), R9: BM=64 (wave owns ONE 16-row
// m-tile). Ps shrinks 18432->9216 B -> LDS 45056 -> 3 blocks/CU (was 2).
// grid (64 q-tiles, 16 key-splits) = 1024 blocks -> 3 resident + 1 queued
// per CU: +50% waves/SIMD for this latency-bound kernel (R6 counters:
// MfmaUtil 9%, VALUBusy 9%, HBM 5% — all pipes idle, TLP-starved).
// 4 chunks of 64 keys per split. NO fences/atomics (R11).
// T14 async-STAGE + s_setprio; last-chunk barriers elided.
// ---------------------------------------------------------------------------
__global__ __launch_bounds__(256) void flash_attn(const __bf16* __restrict__ Q,
                                                  const __bf16* __restrict__ Un_g,
                                                  const __bf16* __restrict__ Ut_g,
                                                  __bf16* __restrict__ O_part,
                                                  float* __restrict__ lp) {
  __shared__ __bf16 Un[64][136];    // [key][d]   stride 272 B (2-way banks)
  __shared__ __bf16 Ut[128][72];    // [d][key]   stride 144 B
  __shared__ __bf16 Ps[4][16][72];  // per-wave P [qrow 0..15][key], wave-private
  const int tid  = threadIdx.x;
  const int w    = tid >> 6;
  const int lane = tid & 63;
  const int quad = lane >> 4;
  const int l16  = lane & 15;
  const int qrow0 = blockIdx.x * 64;
  const int split = blockIdx.y;
  const float scale = 0.08838834764831845f;  // 1/sqrt(128)

  bf16x8 aq[4];
#pragma unroll
  for (int c = 0; c < 4; ++c)
    aq[c] = *(const bf16x8*)(Q + (size_t)(qrow0 + w * 16 + l16) * 128 +
                             c * 32 + quad * 8);

  floatx4 o[8];
#pragma unroll
  for (int t = 0; t < 8; ++t) o[t] = (floatx4){0.f, 0.f, 0.f, 0.f};
  float lsum[4] = {0.f, 0.f, 0.f, 0.f};

  // T14 reg-staging lanes (same footprint as before)
  const int sr = tid >> 4, sc = (tid & 15) * 8;   // Un: rows sr+p*16, col sc
  const int td = tid >> 3, tk = (tid & 7) * 8;    // Ut: d td+p*32, key tk
  bf16x8 un_r[4], ut_r[4];

#define LD_CHUNK(key0)                                                         \
  do {                                                                         \
    _Pragma("unroll")                                                          \
    for (int p = 0; p < 4; ++p)                                                \
      un_r[p] = *(const bf16x8*)(Un_g + (size_t)((key0) + sr + p * 16) * 128 + sc); \
    _Pragma("unroll")                                                          \
    for (int p = 0; p < 4; ++p)                                                \
      ut_r[p] = *(const bf16x8*)(Ut_g + (size_t)(td + p * 32) * 4096 + (key0) + tk); \
  } while (0)

#define ST_CHUNK()                                                             \
  do {                                                                         \
    _Pragma("unroll")                                                          \
    for (int p = 0; p < 4; ++p) *(bf16x8*)&Un[sr + p * 16][sc] = un_r[p];      \
    _Pragma("unroll")                                                          \
    for (int p = 0; p < 4; ++p) *(bf16x8*)&Ut[td + p * 32][tk] = ut_r[p];      \
  } while (0)

  LD_CHUNK(split * 256);
  ST_CHUNK();
  __syncthreads();

  for (int chunk = 0; chunk < 4; ++chunk) {
    if (chunk < 3) LD_CHUNK(split * 256 + (chunk + 1) * 64);  // async prefetch

    // S = Q Uc^T (one m-tile), exp fp32, P -> LDS bf16.
#pragma unroll
    for (int t = 0; t < 4; ++t) {
      bf16x8 bk[4];
#pragma unroll
      for (int c = 0; c < 4; ++c)
        bk[c] = *(const bf16x8*)&Un[t * 16 + l16][c * 32 + quad * 8];
      floatx4 s0 = (floatx4){0.f, 0.f, 0.f, 0.f};
      __builtin_amdgcn_s_setprio(1);
#pragma unroll
      for (int c = 0; c < 4; ++c)
        s0 = __builtin_amdgcn_mfma_f32_16x16x32_bf16(aq[c], bk[c], s0, 0, 0, 0);
      __builtin_amdgcn_s_setprio(0);
#pragma unroll
      for (int r = 0; r < 4; ++r) {
        float p0 = __expf(s0[r] * scale);
        lsum[r] += p0;
        Ps[w][quad * 4 + r][t * 16 + l16] = (__bf16)p0;
      }
    }
    // Ps wave-private: compiler lgkmcnt ordering suffices, no barrier.

    // O += P @ Uc
#pragma unroll
    for (int c2 = 0; c2 < 2; ++c2) {
      bf16x8 ap0 = *(const bf16x8*)&Ps[w][l16][c2 * 32 + quad * 8];
      __builtin_amdgcn_s_setprio(1);
#pragma unroll
      for (int dt = 0; dt < 8; ++dt) {
        bf16x8 bv = *(const bf16x8*)&Ut[dt * 16 + l16][c2 * 32 + quad * 8];
        o[dt] = __builtin_amdgcn_mfma_f32_16x16x32_bf16(ap0, bv, o[dt], 0, 0, 0);
      }
      __builtin_amdgcn_s_setprio(0);
    }

    if (chunk < 3) {
      __syncthreads();  // all waves done reading Un/Ut
      ST_CHUNK();       // implicit vmcnt wait on the prefetched regs
      __syncthreads();
    }
  }
#undef LD_CHUNK
#undef ST_CHUNK

  // Row sums: reduce over the 16 key-columns held across l16.
#pragma unroll
  for (int r = 0; r < 4; ++r) {
    float v = lsum[r];
    v += __shfl_xor(v, 1);
    v += __shfl_xor(v, 2);
    v += __shfl_xor(v, 4);
    v += __shfl_xor(v, 8);
    lsum[r] = v;
  }

  __bf16* Ob = O_part + (size_t)split * 524288;
  const int row0 = qrow0 + w * 16 + quad * 4;
#pragma unroll
  for (int dt = 0; dt < 8; ++dt) {
#pragma unroll
    for (int r = 0; r < 4; ++r) {
      Ob[(size_t)(row0 + r) * 128 + dt * 16 + l16] = (__bf16)o[dt][r];
    }
  }
  if (l16 == 0) {
#pragma unroll
    for (int r = 0; r < 4; ++r) lp[(size_t)split * 4096 + row0 + r] = lsum[r];
  }
}

// ---------------------------------------------------------------------------
// Combine 16 key-splits: out = (sum_s O_s) / (sum_s lp[s][row]). 8 elems/thr.
// ---------------------------------------------------------------------------
__global__ __launch_bounds__(256) void combine_kernel(const __bf16* __restrict__ Op,
                                                      const float* __restrict__ lp,
                                                      float* __restrict__ out) {
  const int i = (blockIdx.x * 256 + threadIdx.x) * 8;  // 0 .. 524287 step 8
  const int row = i >> 7;
  float num[8] = {0.f, 0.f, 0.f, 0.f, 0.f, 0.f, 0.f, 0.f};
  float den = 0.f;
#pragma unroll
  for (int s = 0; s < 16; ++s) {
    bf16x8 v = *(const bf16x8*)(Op + (size_t)s * 524288 + i);
#pragma unroll
    for (int j = 0; j < 8; ++j) num[j] += (float)v[j];
    den += lp[(size_t)s * 4096 + row];
  }
  float inv = 1.f / den;
  float4 r0 = {num[0] * inv, num[1] * inv, num[2] * inv, num[3] * inv};
  float4 r1 = {num[4] * inv, num[5] * inv, num[6] * inv, num[7] * inv};
  *(float4*)(out + i) = r0;
  *(float4*)(out + i + 4) = r1;
}

extern "C" void kernel_launch(void* const* d_in, const int* in_sizes, int n_in,
                              void* d_out, int out_size, void* d_ws, size_t ws_size,
                              hipStream_t stream) {
  (void)in_sizes; (void)n_in; (void)out_size; (void)ws_size;
  const float* ctx      = (const float*)d_in[0];  // [4096,1024]
  const float* ent_embs = (const float*)d_in[1];  // [24636,128]
  const float* W1       = (const float*)d_in[2];  // [768,1024]
  const float* W2       = (const float*)d_in[3];  // [512,768]
  const float* W3       = (const float*)d_in[4];  // [128,512]
  const int*   ent_list = (const int*)d_in[5];    // [4096,50]
  float* out = (float*)d_out;

  // ws layout; peak use ~31 MB (ws is 256 MB).
  char* base = (char*)d_ws;
  __bf16* user_n = (__bf16*)(base);                       // 1 MB
  __bf16* user_t = (__bf16*)(base + (1ull << 20));        // 1 MB
  __bf16* qb     = (__bf16*)(base + (2ull << 20));        // 1 MB
  float*  lp     = (float*)(base + (3ull << 20));         // 256 KB [16][4096]
  f8_t*   ctxb   = (f8_t*)(base + (4ull << 20));          // 4 MB
  f8_t*   W1b    = (f8_t*)(base + (8ull << 20));          // 0.75 MB
  f8_t*   W2b    = (f8_t*)(base + 9175040ull);            // 8.75 MB, 384 KB
  f8_t*   W3b    = (f8_t*)(base + 9568256ull);            // 9.125 MB, 64 KB
  f8_t*   x1b    = (f8_t*)(base + (10ull << 20));         // 3 MB
  f8_t*   x2b    = (f8_t*)(base + (13ull << 20));         // 2 MB
  __bf16* O_part = (__bf16*)(base + (15ull << 20));       // 16 MB (bf16 x 16)

  // 6 dispatches. Critical path: prep -> gemm1 -> gemm2 -> gemm3 -> flash
  // -> combine; pool rides inside dispatch 2, tr inside dispatch 3.
  prep_kernel<<<2432, 256, 0, stream>>>(ctx, ctxb, W1, W1b);
  gemm1_pool<<<1504, 256, 0, stream>>>(ctxb, W1b, x1b, ent_embs, ent_list,
                                       user_n, W2, W2b, W3, W3b);
  gemm2_tr<<<640, 256, 0, stream>>>(x1b, W2b, x2b, user_n, user_t);
  gemm_f8<2, 2, 1, 1, 0, true, 4><<<dim3(4, 128), 256, 0, stream>>>(
      x2b, W3b, qb, 4096, 128, 512);
  flash_attn<<<dim3(64, 16), 256, 0, stream>>>(qb, user_n, user_t, O_part, lp);
  combine_kernel<<<256, 256, 0, stream>>>(O_part, lp, out);
}